// Round 3
// baseline (1522.452 us; speedup 1.0000x reference)
//
#include <hip/hip_runtime.h>
#include <hip/hip_fp16.h>

using half8 = __attribute__((ext_vector_type(8))) _Float16;
using f32x4 = __attribute__((ext_vector_type(4))) float;

union V16 { uint4 u; half8 h; };

__device__ __forceinline__ ushort f2h_bits(float f) {
  return __half_as_ushort(__float2half(f));
}
__device__ __forceinline__ float h2f_lo(unsigned u) {
  return __half2float(__ushort_as_half((ushort)(u & 0xffffu)));
}
__device__ __forceinline__ float h2f_hi(unsigned u) {
  return __half2float(__ushort_as_half((ushort)(u >> 16)));
}

// ---------------------------------------------------------------------------
// prep: W1 [1024,256] fp32 -> W1T [256,1024] fp16 (packed 16B stores);
// zero stats[512]; bag offsets via parallel block scan (block 0).
// ---------------------------------------------------------------------------
__global__ void prep_kernel(const float* __restrict__ W1,
                            const void* __restrict__ bag_sizes,
                            ushort* __restrict__ W1T,
                            float* __restrict__ stats,
                            int* __restrict__ off,
                            int n, int nb, int w1elems) {
  const int t = threadIdx.x;
  const int g = blockIdx.x * 256 + t;
  // packed transpose: thread g produces W1T[g*8 .. g*8+7] (one 16B store)
  if (g < (w1elems >> 3)) {
    const int j = g << 3;        // W1T linear index
    const int nn = j >> 10;      // d_hid index
    const int k = j & 1023;      // d_in index
    unsigned hh[8];
#pragma unroll
    for (int e = 0; e < 8; ++e)
      hh[e] = f2h_bits(W1[(size_t)(k + e) * 256 + nn]);
    uint4 u;
    u.x = hh[0] | (hh[1] << 16);
    u.y = hh[2] | (hh[3] << 16);
    u.z = hh[4] | (hh[5] << 16);
    u.w = hh[6] | (hh[7] << 16);
    *(uint4*)(W1T + j) = u;
  }
  if (g < 512) stats[g] = 0.f;
  if (blockIdx.x == 0) {
    // bag_sizes may be int32 or int64; detect via sum of int32 view == n.
    __shared__ int sb[256];
    __shared__ int tot;
    const int* b32 = (const int*)bag_sizes;
    int v = (t < nb) ? b32[t] : 0;
    sb[t] = v;
    __syncthreads();
#pragma unroll
    for (int d = 128; d; d >>= 1) {
      if (t < d) sb[t] += sb[t + d];
      __syncthreads();
    }
    if (t == 0) tot = sb[0];
    __syncthreads();
    const bool use64 = (tot != n);
    int sz = 0;
    if (t < nb) sz = use64 ? (int)((const long long*)bag_sizes)[t] : b32[t];
    __syncthreads();
    sb[t] = sz;
    __syncthreads();
    // Hillis-Steele inclusive scan over 256 slots (zeros beyond nb)
    for (int d = 1; d < 256; d <<= 1) {
      int x = (t >= d) ? sb[t - d] : 0;
      __syncthreads();
      sb[t] += x;
      __syncthreads();
    }
    if (t < nb) off[t + 1] = sb[t];
    if (t == 0) off[0] = 0;
  }
}

// ---------------------------------------------------------------------------
// gemm1: h = features @ W1 + b1 (fp16 MFMA), H stored fp16 [n,256].
// Tile 64(M) x 256(N) x 64(K), 256 thr = 4 waves, wave tile 64x64.
// A: reg-prefetched fp32 -> fp16, XOR-swizzled LDS, true double-buffer,
//    ONE barrier per K-step.
// B: NO LDS - W1T is L2-resident (512 KB, shared by all blocks); fragments
//    loaded straight to regs, double-buffered one K-step ahead.
// Fused: per-column sum/sumsq (BN stats) in the epilogue -> atomics.
// ---------------------------------------------------------------------------
__global__ __launch_bounds__(256, 2) void gemm1_kernel(
    const float* __restrict__ A,   // [n,1024] fp32
    const ushort* __restrict__ BT, // [256,1024] fp16 (W1 transposed)
    const float* __restrict__ b1,  // [256]
    ushort* __restrict__ H,        // [n,256] fp16 out
    float* __restrict__ stats,     // [512]: colsum, colsumsq
    int n) {
  __shared__ __align__(16) char smem[32768]; // A dbuf 2x8KB; reused as bounce
  const int t = threadIdx.x;
  const int lane = t & 63;
  const int w = t >> 6;        // wave id -> 64-col block
  const int lid = lane & 15;
  const int quad = lane >> 4;  // 0..3
  const long rowBase = (long)blockIdx.x * 64;

  // ---- A staging mapping: per i in 0..3, row = i*16 + sr, float4 chunk c4
  const int sr = t >> 4;  // 0..15
  const int c4 = t & 15;  // 0..15
  const float* aptr[4];
#pragma unroll
  for (int i = 0; i < 4; ++i) {
    long row = rowBase + i * 16 + sr;
    if (row >= n) row = n - 1;  // n%64==0 in this problem; clamp is safety
    aptr[i] = A + row * 1024 + c4 * 4;
  }
  int stOff[4];  // swizzled LDS byte offsets (8B granules)
#pragma unroll
  for (int i = 0; i < 4; ++i) {
    int r = i * 16 + sr;
    stOff[i] = r * 128 + (((c4 >> 1) ^ (r & 7)) << 4) + ((c4 & 1) << 3);
  }
  // ---- B fragment base pointers (per ni), imm offsets walk K
  const ushort* bptr[4];
#pragma unroll
  for (int ni = 0; ni < 4; ++ni)
    bptr[ni] = BT + (size_t)(w * 64 + ni * 16 + lid) * 1024 + quad * 8;
  // ---- A fragment LDS read offsets
  int frOff[4];
#pragma unroll
  for (int mi = 0; mi < 4; ++mi) frOff[mi] = (mi * 16 + lid) * 128;
  int frx[2];
#pragma unroll
  for (int kq = 0; kq < 2; ++kq) frx[kq] = ((kq * 4 + quad) ^ (lid & 7)) << 4;

  f32x4 acc[4][4] = {};
  float4 R[4];           // A global prefetch regs (next K-step)
  uint4 fb0[2][4], fb1[2][4];  // B frag double buffer (named: no dyn indexing)

  auto loadA = [&](int k0) {
#pragma unroll
    for (int i = 0; i < 4; ++i) R[i] = *(const float4*)(aptr[i] + k0);
  };
  auto stageA = [&](int buf) {
    char* base = smem + buf * 8192;
#pragma unroll
    for (int i = 0; i < 4; ++i) {
      uint2 u;
      u.x = (unsigned)f2h_bits(R[i].x) | ((unsigned)f2h_bits(R[i].y) << 16);
      u.y = (unsigned)f2h_bits(R[i].z) | ((unsigned)f2h_bits(R[i].w) << 16);
      *(uint2*)(base + stOff[i]) = u;
    }
  };
  auto loadB0 = [&](int k0) {
#pragma unroll
    for (int kq = 0; kq < 2; ++kq)
#pragma unroll
      for (int ni = 0; ni < 4; ++ni)
        fb0[kq][ni] = *(const uint4*)(bptr[ni] + k0 + kq * 32);
  };
  auto loadB1 = [&](int k0) {
#pragma unroll
    for (int kq = 0; kq < 2; ++kq)
#pragma unroll
      for (int ni = 0; ni < 4; ++ni)
        fb1[kq][ni] = *(const uint4*)(bptr[ni] + k0 + kq * 32);
  };
  auto computeStep = [&](const uint4 (&fb)[2][4], int pp) {
    const char* base = smem + pp * 8192;
#pragma unroll
    for (int kq = 0; kq < 2; ++kq) {
      half8 fa[4];
#pragma unroll
      for (int mi = 0; mi < 4; ++mi) {
        V16 v;
        v.u = *(const uint4*)(base + frOff[mi] + frx[kq]);
        fa[mi] = v.h;
      }
#pragma unroll
      for (int mi = 0; mi < 4; ++mi)
#pragma unroll
        for (int ni = 0; ni < 4; ++ni) {
          V16 b;
          b.u = fb[kq][ni];
          acc[mi][ni] = __builtin_amdgcn_mfma_f32_16x16x32_f16(
              fa[mi], b.h, acc[mi][ni], 0, 0, 0);
        }
    }
  };

  // prologue
  loadA(0);
  loadB0(0);
  stageA(0);   // buf0 <- A(k=0)
  loadA(64);   // R <- A(k=1)
  __syncthreads();

#pragma unroll
  for (int kk = 0; kk < 8; ++kk) {
    const int ks = kk * 2;
    { // even step: compute buf0/fb0; stage buf1 <- A(ks+1); fb1 <- B(ks+1)
      stageA(1);
      if (ks < 14) loadA((ks + 2) * 64);
      loadB1((ks + 1) * 64);
      computeStep(fb0, 0);
      __syncthreads();
    }
    { // odd step: compute buf1/fb1; stage buf0 <- A(ks+2); fb0 <- B(ks+2)
      if (ks + 1 < 15) {
        stageA(0);
        if (ks + 1 < 14) loadA((ks + 3) * 64);  // guard: A(15) must be loaded
        loadB0((ks + 2) * 64);
      }
      computeStep(fb1, 1);
      __syncthreads();
    }
  }

  // epilogue: +b1, fp16 round, fused column stats, LDS bounce for 16B stores
  ushort* bounce = (ushort*)smem;  // 64x256 fp16 = 32KB
  float bv[4];
#pragma unroll
  for (int ni = 0; ni < 4; ++ni) bv[ni] = b1[w * 64 + ni * 16 + lid];
  float cs[4] = {0.f, 0.f, 0.f, 0.f};
  float cq[4] = {0.f, 0.f, 0.f, 0.f};
#pragma unroll
  for (int mi = 0; mi < 4; ++mi)
#pragma unroll
    for (int ni = 0; ni < 4; ++ni)
#pragma unroll
      for (int r = 0; r < 4; ++r) {
        int row = mi * 16 + quad * 4 + r;  // C/D: row=(lane>>4)*4+reg
        int col = w * 64 + ni * 16 + lid;  // col=lane&15
        float v = acc[mi][ni][r] + bv[ni];
        bounce[row * 256 + col] = f2h_bits(v);
        cs[ni] += v;
        cq[ni] += v * v;
      }
  // reduce the 64-row column partials across the 4 quads (lanes ^16, ^32)
#pragma unroll
  for (int ni = 0; ni < 4; ++ni) {
    cs[ni] += __shfl_xor(cs[ni], 16);
    cs[ni] += __shfl_xor(cs[ni], 32);
    cq[ni] += __shfl_xor(cq[ni], 16);
    cq[ni] += __shfl_xor(cq[ni], 32);
  }
  if (quad == 0) {
#pragma unroll
    for (int ni = 0; ni < 4; ++ni) {
      int col = w * 64 + ni * 16 + lid;
      atomicAdd(&stats[col], cs[ni]);
      atomicAdd(&stats[256 + col], cq[ni]);
    }
  }
  __syncthreads();
  const uint4* bU = (const uint4*)smem;
#pragma unroll
  for (int i = 0; i < 8; ++i) {
    int cid = i * 256 + t;
    int row = cid >> 5, cc = cid & 31;
    long grow = rowBase + row;
    if (grow < n) *(uint4*)(H + grow * 256 + cc * 8) = bU[row * 32 + cc];
  }
}

// ---------------------------------------------------------------------------
// finalize: BN folded into per-col affine a,c; copy w2. (b2 cancels in softmax)
// ---------------------------------------------------------------------------
__global__ void finalize_kernel(const float* __restrict__ stats,
                                const float* __restrict__ gamma,
                                const float* __restrict__ beta,
                                const float* __restrict__ W2,
                                float* __restrict__ acw, float inv_n) {
  int t = threadIdx.x;  // 256
  float mean = stats[t] * inv_n;
  float var = stats[256 + t] * inv_n - mean * mean;
  float inv = rsqrtf(var + 1e-5f);
  float a = gamma[t] * inv;
  acw[t] = a;
  acw[256 + t] = beta[t] - mean * a;
  acw[512 + t] = W2[t];
}

// ---------------------------------------------------------------------------
// scores: s[r] = sum_col relu(a*h + c) * w2. Coalesced: 32 lanes per row
// (16B each), 5-step shuffle reduce. grid = 1024 blocks.
// ---------------------------------------------------------------------------
__global__ __launch_bounds__(256) void scores_kernel(
    const ushort* __restrict__ H, const float* __restrict__ acw,
    float* __restrict__ scores, int n) {
  __shared__ float sa[256], sc[256], sw[256];
  const int t = threadIdx.x;
  sa[t] = acw[t];
  sc[t] = acw[256 + t];
  sw[t] = acw[512 + t];
  __syncthreads();
  const int cg = t & 31;  // column chunk (8 cols, 16B)
  const int rg = t >> 5;  // 8 row slots per block-iter
  const int rpb = n >> 10;  // rows per block (grid 1024)
  const long rbase = (long)blockIdx.x * rpb;
  const int iters = rpb >> 3;
  float a0[8], c0[8], w0[8];
#pragma unroll
  for (int j = 0; j < 8; ++j) {
    a0[j] = sa[cg * 8 + j];
    c0[j] = sc[cg * 8 + j];
    w0[j] = sw[cg * 8 + j];
  }
  for (int i = 0; i < iters; ++i) {
    long r = rbase + (long)i * 8 + rg;
    uint4 u = *(const uint4*)(H + r * 256 + cg * 8);
    unsigned uu[4] = {u.x, u.y, u.z, u.w};
    float s = 0.f;
#pragma unroll
    for (int p = 0; p < 4; ++p) {
      float x0 = h2f_lo(uu[p]), x1 = h2f_hi(uu[p]);
      s += fmaxf(fmaf(a0[2 * p], x0, c0[2 * p]), 0.f) * w0[2 * p];
      s += fmaxf(fmaf(a0[2 * p + 1], x1, c0[2 * p + 1]), 0.f) * w0[2 * p + 1];
    }
#pragma unroll
    for (int o = 16; o; o >>= 1) s += __shfl_xor(s, o);
    if (cg == 0) scores[r] = s;
  }
}

// ---------------------------------------------------------------------------
// softmax: one block per bag, 3-phase (max, sumexp, write)
// ---------------------------------------------------------------------------
__global__ __launch_bounds__(256) void softmax_kernel(
    const float* __restrict__ scores, const int* __restrict__ off,
    float* __restrict__ out) {
  const int b = blockIdx.x;
  const int start = off[b], end = off[b + 1];
  const int t = threadIdx.x;
  const int lane = t & 63, wid = t >> 6;
  __shared__ float red[8];
  float m = -INFINITY;
  for (int r = start + t; r < end; r += 256) m = fmaxf(m, scores[r]);
#pragma unroll
  for (int o = 32; o; o >>= 1) m = fmaxf(m, __shfl_xor(m, o));
  if (lane == 0) red[wid] = m;
  __syncthreads();
  if (t == 0)
    red[0] = fmaxf(fmaxf(red[0], red[1]), fmaxf(red[2], red[3]));
  __syncthreads();
  m = red[0];
  float z = 0.f;
  for (int r = start + t; r < end; r += 256) z += __expf(scores[r] - m);
#pragma unroll
  for (int o = 32; o; o >>= 1) z += __shfl_xor(z, o);
  if (lane == 0) red[4 + wid] = z;
  __syncthreads();
  z = red[4] + red[5] + red[6] + red[7];
  float invz = 1.0f / z;
  for (int r = start + t; r < end; r += 256)
    out[r] = __expf(scores[r] - m) * invz;
}

// ---------------------------------------------------------------------------
extern "C" void kernel_launch(void* const* d_in, const int* in_sizes, int n_in,
                              void* d_out, int out_size, void* d_ws,
                              size_t ws_size, hipStream_t stream) {
  const float* features = (const float*)d_in[0];
  const void* bag_sizes = d_in[1];
  const float* W1 = (const float*)d_in[2];
  const float* b1 = (const float*)d_in[3];
  const float* gamma = (const float*)d_in[4];
  const float* beta = (const float*)d_in[5];
  const float* W2 = (const float*)d_in[6];
  // d_in[7] = b2: cancels inside per-bag softmax, unused.

  const int n = in_sizes[0] / 1024;  // rows (262144)
  const int nb = in_sizes[1];        // bags (128)
  const int w1elems = in_sizes[2];   // 262144

  char* ws = (char*)d_ws;
  ushort* W1T = (ushort*)ws;                               // 512 KB fp16
  ushort* H = (ushort*)(ws + 524288);                      // n*256 fp16
  float* stats = (float*)(ws + 524288 + (size_t)n * 512);  // 512 fp32
  float* acw = stats + 512;                                // 768 fp32
  float* scores = acw + 768;                               // n fp32
  int* off = (int*)(scores + n);                           // nb+1 ints

  prep_kernel<<<((w1elems >> 3) + 255) / 256, 256, 0, stream>>>(
      W1, bag_sizes, W1T, stats, off, n, nb, w1elems);
  gemm1_kernel<<<(n + 63) / 64, 256, 0, stream>>>(features, W1T, b1, H, stats,
                                                  n);
  finalize_kernel<<<1, 256, 0, stream>>>(stats, gamma, beta, W2, acw,
                                         1.0f / (float)n);
  scores_kernel<<<1024, 256, 0, stream>>>(H, acw, scores, n);
  softmax_kernel<<<nb, 256, 0, stream>>>(scores, off, (float*)d_out);
}